// Round 15
// baseline (18412.877 us; speedup 1.0000x reference)
//
#include <hip/hip_runtime.h>

typedef unsigned short u16;
typedef __attribute__((ext_vector_type(8))) short short8;
typedef __attribute__((ext_vector_type(4))) float f32x4;

#define AXR __ATOMIC_RELAXED, __HIP_MEMORY_SCOPE_AGENT

__device__ __forceinline__ float bf2f(u16 v){
  union { unsigned u; float f; } t; t.u = ((unsigned)v) << 16; return t.f;
}
__device__ __forceinline__ u16 f2bf(float f){
  union { float f; unsigned u; } t; t.f = f;
  unsigned u = t.u;
  return (u16)((u + 0x7fffu + ((u >> 16) & 1u)) >> 16);
}
struct HiLo { short hi, lo; };
__device__ __forceinline__ HiLo split1(float v){
  HiLo r;
  u16 h = f2bf(v);
  r.hi = (short)h;
  r.lo = (short)f2bf(v - bf2f(h));
  return r;
}
__device__ __forceinline__ void ldw8s(const float* __restrict__ p, short8& hi, short8& lo){
  #pragma unroll
  for (int j = 0; j < 8; ++j){ HiLo s = split1(p[j]); hi[j] = s.hi; lo[j] = s.lo; }
}

#define MFMA(acc, a, b) acc = __builtin_amdgcn_mfma_f32_16x16x32_bf16(a, b, acc, 0,0,0)
#define SMACC(acc, ah, al, bh, bl) do{ MFMA(acc, ah, bh); MFMA(acc, ah, bl); MFMA(acc, al, bh); }while(0)

// ---- prepass: f32 -> (hi,lo) bf16 ------------------------------------------
__global__ void wsplit(const float* __restrict__ s, u16* __restrict__ hi,
                       u16* __restrict__ lo, int n){
  int i = blockIdx.x * blockDim.x + threadIdx.x;
  if (i < n){ HiLo r = split1(s[i]); hi[i] = (u16)r.hi; lo[i] = (u16)r.lo; }
}

// ---- prepass: Wcomb = Wih0 @ Wout (2048x512, split), bb = b0 + Wih0@bout ---
__global__ void __launch_bounds__(256) wcomb_k(
    const float* __restrict__ Wih0, const float* __restrict__ Wout,
    const float* __restrict__ bout, const float* __restrict__ bih0,
    const float* __restrict__ bhh0,
    u16* __restrict__ Wch, u16* __restrict__ Wcl, float* __restrict__ bb)
{
  __shared__ float wl[8*64];
  __shared__ float bo[64];
  const int wg = blockIdx.x, tid = threadIdx.x;
  const int r0 = wg*8;
  for (int i = tid; i < 512; i += 256) wl[i] = Wih0[(r0 + (i >> 6))*64 + (i & 63)];
  if (tid < 64) bo[tid] = bout[tid];
  __syncthreads();
  if (tid < 8){
    int n = r0 + tid;
    float a = bih0[n] + bhh0[n];
    #pragma unroll 8
    for (int d = 0; d < 64; ++d) a += wl[tid*64 + d]*bo[d];
    bb[n] = a;
  }
  #pragma unroll
  for (int jj = 0; jj < 2; ++jj){
    int j = tid + jj*256;
    float acc[8] = {0,0,0,0,0,0,0,0};
    for (int d = 0; d < 64; ++d){
      float wv = Wout[d*512 + j];
      #pragma unroll
      for (int r = 0; r < 8; ++r) acc[r] += wl[r*64 + d]*wv;
    }
    #pragma unroll
    for (int r = 0; r < 8; ++r){
      HiLo s = split1(acc[r]);
      Wch[(r0 + r)*512 + j] = (u16)s.hi;
      Wcl[(r0 + r)*512 + j] = (u16)s.lo;
    }
  }
}

// ---- init-only tree barrier (threadfence-based, proven R13/R14) ------------
__device__ __forceinline__ void gbar(unsigned* bar, unsigned phase){
  __syncthreads();
  if (threadIdx.x == 0){
    __threadfence();
    const unsigned gg = (unsigned)blockIdx.x >> 4;
    unsigned old = __hip_atomic_fetch_add(bar + 64 + gg*32, 1u, AXR);
    if (old == phase*16u - 1u){
      unsigned r = __hip_atomic_fetch_add(bar, 1u, AXR);
      if (r == phase*16u - 1u)
        __hip_atomic_store(bar + 32, phase, AXR);
    }
    while (__hip_atomic_load(bar + 32, AXR) < phase)
      __builtin_amdgcn_s_sleep(2);
    __threadfence();
  }
  __syncthreads();
}

// ---- global fallback barrier (R14 xbar, any WG placement) ------------------
__device__ __forceinline__ void xbar(unsigned* bar, unsigned phase,
                                     unsigned xcd, unsigned pop, unsigned nx){
  __syncthreads();
  if (threadIdx.x == 0){
    unsigned old = __hip_atomic_fetch_add(bar + 832 + xcd*32, 1u, AXR);
    const bool leader = (old == phase*pop - 1u);
    if (leader){
      asm volatile("buffer_wbl2 sc1\n\ts_waitcnt vmcnt(0)" ::: "memory");
      unsigned r = __hip_atomic_fetch_add(bar + 1344, 1u, AXR);
      if (r == phase*nx - 1u)
        __hip_atomic_store(bar + 1376, phase, AXR);
    }
    while (__hip_atomic_load(bar + 1376, AXR) < phase)
      __builtin_amdgcn_s_sleep(2);
    if (leader){
      asm volatile("buffer_inv sc1\n\ts_waitcnt vmcnt(0)" ::: "memory");
      __hip_atomic_store(bar + 1088 + xcd*32, phase, AXR);
    } else {
      while (__hip_atomic_load(bar + 1088 + xcd*32, AXR) < phase)
        __builtin_amdgcn_s_sleep(1);
      asm volatile("buffer_inv\n\ts_waitcnt vmcnt(0)" ::: "memory");
    }
  }
  __syncthreads();
}

// ---- group-local barrier (requires group co-located on one XCD) ------------
// Stores reach the XCD's L2 via write-through vL1 + syncthreads' vmcnt drain.
// Acquire = vL1 invalidate only: NO L2 writeback, NO L2 invalidate.
__device__ __forceinline__ void pbar(unsigned* bar, unsigned g, unsigned phase){
  __syncthreads();
  if (threadIdx.x == 0){
    unsigned* ctr = bar + 2048 + g*32;
    __hip_atomic_fetch_add(ctr, 1u, AXR);
    while (__hip_atomic_load(ctr, AXR) < phase*32u)
      __builtin_amdgcn_s_sleep(1);
    asm volatile("buffer_inv\n\ts_waitcnt vmcnt(0)" ::: "memory");
  }
  __syncthreads();
}

// ---- LDS weight-slice helpers (XOR-swizzled, G4) ---------------------------
__device__ __forceinline__ short8 lds8(const u16* base, int r, int kelem, int rowbytes){
  int bo = r*rowbytes + ((kelem*2) ^ ((r & 7) << 4));
  return *(const short8*)((const char*)base + bo);
}
// 64 gate rows (4 gates x 16 cols of col-group cg) x ldw K
__device__ __forceinline__ void load_slice64(
    const float* __restrict__ W, int ldw, int rowshift, int nelem,
    u16* lh, u16* ll, int cg, int tid)
{
  const int rowbytes = ldw*2;
  for (int i = tid; i < nelem; i += 256){
    int r = i >> rowshift, k = i & ((1 << rowshift) - 1);
    int n = ((r >> 4) << 9) + cg*16 + (r & 15);
    HiLo s = split1(W[n*ldw + k]);
    int bo = r*rowbytes + ((k*2) ^ ((r & 7) << 4));
    *(u16*)((char*)lh + bo) = (u16)s.hi;
    *(u16*)((char*)ll + bo) = (u16)s.lo;
  }
}

// ---- persistent kernel: batch-parallel groups, XCD-local exchange ----------
// group g = wg&7 owns batches [g*32, +32); col-group cg = wg>>3 owns 16 cols.
// wave wv = gate wv (16 gate rows); 2 M-tiles of 16 batches.
__global__ void __launch_bounds__(256, 1) lstm_persist(
    const float* __restrict__ x,
    const float* __restrict__ Whh0, const float* __restrict__ Wih0,
    const u16* __restrict__ W1ih_h, const u16* __restrict__ W1ih_l,
    const u16* __restrict__ W1hh_h, const u16* __restrict__ W1hh_l,
    const u16* __restrict__ Wcmb_h, const u16* __restrict__ Wcmb_l,
    const float* __restrict__ bb,
    const float* __restrict__ bih0, const float* __restrict__ bhh0,
    const float* __restrict__ bih1, const float* __restrict__ bhh1,
    const float* __restrict__ Wout, const float* __restrict__ bout,
    float* __restrict__ out, unsigned* __restrict__ cnt,
    u16* __restrict__ h0h0, u16* __restrict__ h0h1,
    u16* __restrict__ h0l0, u16* __restrict__ h0l1,
    u16* __restrict__ h1h0, u16* __restrict__ h1h1,
    u16* __restrict__ h1l0, u16* __restrict__ h1l1)
{
  __shared__ u16 whh0_h[32768], whh0_l[32768];   // 64x512, swizzled
  __shared__ u16 w0ih_h[4096],  w0ih_l[4096];    // 64x64, swizzled
  __shared__ float gl[32*68];                    // gate exchange [m][4*16+pad]
  __shared__ float pr[256];                      // pred partials [d][kq]
  __shared__ float bs0[64], bs1[64], bsd[64];
  __shared__ unsigned s_pop, s_nx, s_all;

  const int wg = blockIdx.x, tid = threadIdx.x;
  const int g = wg & 7, cg = wg >> 3;
  const int b0 = g*32;
  const int lane = tid & 63, wv = tid >> 6;
  const int cI = lane & 15;
  const int kc = (lane >> 4) << 3;
  const int rl = wv*16 + cI;                     // local gate row

  // ---- one-time init: LDS weight slices + biases ----
  load_slice64(Whh0, 512, 9, 32768, whh0_h, whh0_l, cg, tid);
  load_slice64(Wih0,  64, 6,  4096, w0ih_h, w0ih_l, cg, tid);
  if (tid < 64){
    int n = ((tid >> 4) << 9) + cg*16 + (tid & 15);
    bs0[tid] = bih0[n] + bhh0[n];
    bs1[tid] = bih1[n] + bhh1[n];
    bsd[tid] = bb[n];
  }

  // ---- census: XCD id, per-XCD pop (for fallback), group co-location ----
  unsigned xcd;
  asm volatile("s_getreg_b32 %0, hwreg(HW_REG_XCC_ID)" : "=s"(xcd));
  xcd &= 7u;
  if (tid == 0){
    __hip_atomic_fetch_add(cnt + 576 + xcd*32, 1u, AXR);
    __hip_atomic_store(cnt + 1536 + wg, xcd, AXR);
  }
  gbar(cnt, 1);
  if (tid == 0){
    unsigned nxl = 0;
    for (int i = 0; i < 8; ++i)
      nxl += (__hip_atomic_load(cnt + 576 + i*32, AXR) != 0u) ? 1u : 0u;
    s_pop = __hip_atomic_load(cnt + 576 + xcd*32, AXR);
    s_nx  = nxl;
    unsigned ok = 1;
    for (int i = 0; i < 32; ++i)
      ok &= (__hip_atomic_load(cnt + 1536 + (g + 8*i), AXR) == xcd) ? 1u : 0u;
    if (!ok) __hip_atomic_store(cnt + 1800 + g, 1u, AXR);
  }
  gbar(cnt, 2);
  if (tid == 0){
    unsigned bad = 0;
    for (int gg = 0; gg < 8; ++gg)
      bad |= __hip_atomic_load(cnt + 1800 + gg, AXR);
    s_all = (bad == 0u) ? 1u : 0u;
  }
  __syncthreads();
  const unsigned pop = s_pop, nx = s_nx;
  const bool allco = (s_all != 0u);

  const int ar0 = b0 + cI, ar1 = b0 + 16 + cI;   // A rows (batches)
  const int aoff0 = ar0*512 + kc, aoff1 = ar1*512 + kc;
  const int nb = (wv*512 + cg*16 + cI)*512 + kc; // streamed weight frag base

  u16* H0h[2] = { h0h0, h0h1 };  u16* H0l[2] = { h0l0, h0l1 };
  u16* H1h[2] = { h1h0, h1h1 };  u16* H1l[2] = { h1l0, h1l1 };

  const float* xb0 = x + ar0*21504;
  const float* xb1 = x + ar1*21504;

  float c0r[2] = {0.f, 0.f}, c1r[2] = {0.f, 0.f};   // cell state in registers
  unsigned ep = 0;

  for (int t = 0; t < 432; ++t){
    const int p = t & 1;
    const bool enc = (t < 336);

    // =============== phase A: layer 0 ===============
    f32x4 A0 = {0,0,0,0}, A1 = {0,0,0,0};
    if (enc){
      #pragma unroll
      for (int ks = 0; ks < 2; ++ks){            // x segment (K=64)
        int k = ks*32 + kc;
        short8 a0h, a0l, a1h, a1l;
        #pragma unroll
        for (int j = 0; j < 8; ++j){
          HiLo s0 = split1(xb0[(k + j)*336 + t]); a0h[j] = s0.hi; a0l[j] = s0.lo;
          HiLo s1 = split1(xb1[(k + j)*336 + t]); a1h[j] = s1.hi; a1l[j] = s1.lo;
        }
        short8 bh = lds8(w0ih_h, rl, k, 128);
        short8 bl = lds8(w0ih_l, rl, k, 128);
        SMACC(A0, a0h, a0l, bh, bl);
        SMACC(A1, a1h, a1l, bh, bl);
      }
    } else if (t > 336){                         // Wcomb segment over h1_{t-1}
      const u16* hH = H1h[p^1]; const u16* hL = H1l[p^1];
      const u16* wh = Wcmb_h + nb; const u16* wl_ = Wcmb_l + nb;
      #pragma unroll 4
      for (int ks = 0; ks < 16; ++ks){
        int k = ks*32;
        short8 a0h = *(const short8*)(hH + aoff0 + k);
        short8 a0l = *(const short8*)(hL + aoff0 + k);
        short8 a1h = *(const short8*)(hH + aoff1 + k);
        short8 a1l = *(const short8*)(hL + aoff1 + k);
        short8 bh = *(const short8*)(wh + k);
        short8 bl = *(const short8*)(wl_ + k);
        SMACC(A0, a0h, a0l, bh, bl);
        SMACC(A1, a1h, a1l, bh, bl);
      }
    }
    {                                            // Whh0 (LDS) over h0_{t-1}
      const u16* hH = H0h[p^1]; const u16* hL = H0l[p^1];
      #pragma unroll 4
      for (int ks = 0; ks < 16; ++ks){
        int k = ks*32;
        short8 a0h = *(const short8*)(hH + aoff0 + k);
        short8 a0l = *(const short8*)(hL + aoff0 + k);
        short8 a1h = *(const short8*)(hH + aoff1 + k);
        short8 a1l = *(const short8*)(hL + aoff1 + k);
        short8 bh = lds8(whh0_h, rl, kc + k, 1024);
        short8 bl = lds8(whh0_l, rl, kc + k, 1024);
        SMACC(A0, a0h, a0l, bh, bl);
        SMACC(A1, a1h, a1l, bh, bl);
      }
    }
    // decoder pred l=t-337 from h1_{t-1}: this WG owns batch b0+cg
    if (!enc && t > 336){
      const int d = tid & 63, kq = tid >> 6;
      const int b = b0 + cg;
      const u16* hH = H1h[p^1] + b*512 + kq*128;
      const u16* hL = H1l[p^1] + b*512 + kq*128;
      const float* wr = Wout + d*512 + kq*128;
      float part = 0.f;
      #pragma unroll 4
      for (int k = 0; k < 128; k += 8){
        short8 hv = *(const short8*)(hH + k);
        short8 lv = *(const short8*)(hL + k);
        #pragma unroll
        for (int j = 0; j < 8; ++j)
          part += (bf2f((u16)hv[j]) + bf2f((u16)lv[j])) * wr[k + j];
      }
      pr[d*4 + kq] = part;
      __syncthreads();
      if (tid < 64){
        float v = pr[tid*4] + pr[tid*4+1] + pr[tid*4+2] + pr[tid*4+3] + bout[tid];
        out[131072 + (b*64 + tid)*96 + (t - 337)] = v;
      }
    }
    // cell update layer 0 (c in registers)
    {
      const float* bias = (enc || t == 336) ? bs0 : bsd;
      __syncthreads();
      const int rb_ = (lane >> 4) << 2;
      #pragma unroll
      for (int r = 0; r < 4; ++r){
        gl[(rb_ + r)*68 + rl]      = A0[r] + bias[rl];
        gl[(16 + rb_ + r)*68 + rl] = A1[r] + bias[rl];
      }
      __syncthreads();
      u16* Hh = H0h[p]; u16* Hl = H0l[p];
      #pragma unroll
      for (int q = 0; q < 2; ++q){
        int e = tid + q*256;
        int m = e >> 4, col = e & 15;
        float iv = gl[m*68 + col];
        float fv = gl[m*68 + 16 + col];
        float gv = gl[m*68 + 32 + col];
        float ov = gl[m*68 + 48 + col];
        float si = 1.f/(1.f + expf(-iv));
        float sf = 1.f/(1.f + expf(-fv));
        float so = 1.f/(1.f + expf(-ov));
        float cn = sf*c0r[q] + si*tanhf(gv);
        c0r[q] = cn;
        float h = so*tanhf(cn);
        int gi = (b0 + m)*512 + cg*16 + col;
        u16 hh = f2bf(h);
        Hh[gi] = hh;
        Hl[gi] = f2bf(h - bf2f(hh));
      }
    }
    ++ep;
    if (allco) pbar(cnt, g, ep); else xbar(cnt, ep, xcd, pop, nx);

    // =============== phase B: layer 1 ===============
    A0 = (f32x4){0,0,0,0}; A1 = (f32x4){0,0,0,0};
    {
      const u16* hH = H0h[p]; const u16* hL = H0l[p];      // h0_t
      const u16* wh = W1ih_h + nb; const u16* wl_ = W1ih_l + nb;
      #pragma unroll 4
      for (int ks = 0; ks < 16; ++ks){
        int k = ks*32;
        short8 a0h = *(const short8*)(hH + aoff0 + k);
        short8 a0l = *(const short8*)(hL + aoff0 + k);
        short8 a1h = *(const short8*)(hH + aoff1 + k);
        short8 a1l = *(const short8*)(hL + aoff1 + k);
        short8 bh = *(const short8*)(wh + k);
        short8 bl = *(const short8*)(wl_ + k);
        SMACC(A0, a0h, a0l, bh, bl);
        SMACC(A1, a1h, a1l, bh, bl);
      }
    }
    {
      const u16* hH = H1h[p^1]; const u16* hL = H1l[p^1];  // h1_{t-1}
      const u16* wh = W1hh_h + nb; const u16* wl_ = W1hh_l + nb;
      #pragma unroll 4
      for (int ks = 0; ks < 16; ++ks){
        int k = ks*32;
        short8 a0h = *(const short8*)(hH + aoff0 + k);
        short8 a0l = *(const short8*)(hL + aoff0 + k);
        short8 a1h = *(const short8*)(hH + aoff1 + k);
        short8 a1l = *(const short8*)(hL + aoff1 + k);
        short8 bh = *(const short8*)(wh + k);
        short8 bl = *(const short8*)(wl_ + k);
        SMACC(A0, a0h, a0l, bh, bl);
        SMACC(A1, a1h, a1l, bh, bl);
      }
    }
    // cell update layer 1
    {
      float* gf = (t == 335) ? out : (float*)nullptr;
      __syncthreads();
      const int rb_ = (lane >> 4) << 2;
      #pragma unroll
      for (int r = 0; r < 4; ++r){
        gl[(rb_ + r)*68 + rl]      = A0[r] + bs1[rl];
        gl[(16 + rb_ + r)*68 + rl] = A1[r] + bs1[rl];
      }
      __syncthreads();
      u16* Hh = H1h[p]; u16* Hl = H1l[p];
      #pragma unroll
      for (int q = 0; q < 2; ++q){
        int e = tid + q*256;
        int m = e >> 4, col = e & 15;
        float iv = gl[m*68 + col];
        float fv = gl[m*68 + 16 + col];
        float gv = gl[m*68 + 32 + col];
        float ov = gl[m*68 + 48 + col];
        float si = 1.f/(1.f + expf(-iv));
        float sf = 1.f/(1.f + expf(-fv));
        float so = 1.f/(1.f + expf(-ov));
        float cn = sf*c1r[q] + si*tanhf(gv);
        c1r[q] = cn;
        float h = so*tanhf(cn);
        int gi = (b0 + m)*512 + cg*16 + col;
        u16 hh = f2bf(h);
        Hh[gi] = hh;
        Hl[gi] = f2bf(h - bf2f(hh));
        if (gf) gf[gi] = h;
      }
    }
    ++ep;
    if (allco) pbar(cnt, g, ep); else xbar(cnt, ep, xcd, pop, nx);
  }
}

// ---- tail: pred for l=95 from h1_431 (parity 1) ----------------------------
__global__ void __launch_bounds__(256) pred_last(
    const u16* __restrict__ h1hi, const u16* __restrict__ h1lo,
    const float* __restrict__ Wout, const float* __restrict__ bout,
    float* __restrict__ out)
{
  const int wg = blockIdx.x, tid = threadIdx.x;
  const int bsub = tid >> 6, d = tid & 63;
  const int b = wg*4 + bsub;
  float acc = bout[d];
  const u16* hH = h1hi + b*512;
  const u16* hL = h1lo + b*512;
  const float* wr = Wout + d*512;
  #pragma unroll 8
  for (int k = 0; k < 512; k += 8){
    short8 hv = *(const short8*)(hH + k);
    short8 lv = *(const short8*)(hL + k);
    #pragma unroll
    for (int j = 0; j < 8; ++j)
      acc += (bf2f((u16)hv[j]) + bf2f((u16)lv[j])) * wr[k + j];
  }
  out[131072 + (b*64 + d)*96 + 95] = acc;
}

// ======================= fallback (R9 proven path) ==========================
__device__ __forceinline__ void cell_epilogue_fb(
    float* gl, const float* bs, float* __restrict__ cbuf,
    u16* __restrict__ hhi, u16* __restrict__ hlo,
    float* __restrict__ gfout, int mrow, int jblk,
    const f32x4& a0, const f32x4& a1, int wv, int lane, int tid)
{
  __syncthreads();
  const int rbase = wv*16 + ((lane >> 4) << 2);
  const int cI = lane & 15;
  #pragma unroll
  for (int r = 0; r < 4; ++r){
    gl[(rbase+r)*33 + cI]      = a0[r] + bs[cI];
    gl[(rbase+r)*33 + 16 + cI] = a1[r] + bs[16 + cI];
  }
  __syncthreads();
  #pragma unroll
  for (int q = 0; q < 2; ++q){
    int e = tid + q*256;
    int m = e >> 3, jj = e & 7;
    float iv = gl[m*33 + jj];
    float fv = gl[m*33 + 8 + jj];
    float gv = gl[m*33 + 16 + jj];
    float ov = gl[m*33 + 24 + jj];
    float si = 1.f/(1.f + expf(-iv));
    float sf = 1.f/(1.f + expf(-fv));
    float so = 1.f/(1.f + expf(-ov));
    int gi = (mrow*64 + m)*512 + jblk*8 + jj;
    float cn = sf*cbuf[gi] + si*tanhf(gv);
    cbuf[gi] = cn;
    float h = so*tanhf(cn);
    u16 hh = f2bf(h);
    hhi[gi] = hh;
    hlo[gi] = f2bf(h - bf2f(hh));
    if (gfout) gfout[gi] = h;
  }
}

template<bool ENC>
__global__ void __launch_bounds__(256) l0_fb(
    const float* __restrict__ x,
    const u16* __restrict__ predhi, const u16* __restrict__ predlo,
    const float* __restrict__ Wihf, const float* __restrict__ Whhf,
    const float* __restrict__ bih, const float* __restrict__ bhh,
    const u16* __restrict__ hphi, const u16* __restrict__ hplo,
    u16* __restrict__ hnhi, u16* __restrict__ hnlo,
    float* __restrict__ c0, int t)
{
  __shared__ float gl[64*33];
  __shared__ float bs[32];
  const int wg = blockIdx.x, tid = threadIdx.x;
  const int mrow = wg & 3, jblk = wg >> 2;
  const int lane = tid & 63, wv = tid >> 6;
  if (tid < 32){
    int n = ((tid >> 3) << 9) + jblk*8 + (tid & 7);
    bs[tid] = bih[n] + bhh[n];
  }
  const int ar = mrow*64 + wv*16 + (lane & 15);
  const int kc = (lane >> 4) << 3;
  const int cI = lane & 15;
  const int n0 = ((cI >> 3) << 9) + jblk*8 + (cI & 7);
  const int n1 = n0 + 1024;

  f32x4 acc0 = {0,0,0,0}, acc1 = {0,0,0,0};
  #pragma unroll
  for (int ks = 0; ks < 2; ++ks){
    int k = ks*32 + kc;
    short8 ah, al;
    if (ENC){
      const float* xb = x + ar*21504 + t;
      #pragma unroll
      for (int j = 0; j < 8; ++j){ HiLo s = split1(xb[(k + j)*336]); ah[j] = s.hi; al[j] = s.lo; }
    } else {
      ah = *(const short8*)(predhi + ar*64 + k);
      al = *(const short8*)(predlo + ar*64 + k);
    }
    short8 bh0, bl0, bh1, bl1;
    ldw8s(Wihf + n0*64 + k, bh0, bl0);
    ldw8s(Wihf + n1*64 + k, bh1, bl1);
    SMACC(acc0, ah, al, bh0, bl0);
    SMACC(acc1, ah, al, bh1, bl1);
  }
  const u16* hH = hphi + ar*512 + kc;
  const u16* hL = hplo + ar*512 + kc;
  #pragma unroll 4
  for (int ks = 0; ks < 16; ++ks){
    int k = ks*32;
    short8 ah = *(const short8*)(hH + k);
    short8 al = *(const short8*)(hL + k);
    short8 bh0, bl0, bh1, bl1;
    ldw8s(Whhf + n0*512 + kc + k, bh0, bl0);
    ldw8s(Whhf + n1*512 + kc + k, bh1, bl1);
    SMACC(acc0, ah, al, bh0, bl0);
    SMACC(acc1, ah, al, bh1, bl1);
  }
  cell_epilogue_fb(gl, bs, c0, hnhi, hnlo, nullptr, mrow, jblk, acc0, acc1, wv, lane, tid);
}

__global__ void __launch_bounds__(256) l1_fb(
    const float* __restrict__ Wihf, const float* __restrict__ Whhf,
    const float* __restrict__ bih, const float* __restrict__ bhh,
    const u16* __restrict__ h0hi, const u16* __restrict__ h0lo,
    const u16* __restrict__ h1phi, const u16* __restrict__ h1plo,
    u16* __restrict__ h1nhi, u16* __restrict__ h1nlo,
    float* __restrict__ c1, float* __restrict__ gfout)
{
  __shared__ float gl[64*33];
  __shared__ float bs[32];
  const int wg = blockIdx.x, tid = threadIdx.x;
  const int mrow = wg & 3, jblk = wg >> 2;
  const int lane = tid & 63, wv = tid >> 6;
  if (tid < 32){
    int n = ((tid >> 3) << 9) + jblk*8 + (tid & 7);
    bs[tid] = bih[n] + bhh[n];
  }
  const int ar = mrow*64 + wv*16 + (lane & 15);
  const int kc = (lane >> 4) << 3;
  const int cI = lane & 15;
  const int n0 = ((cI >> 3) << 9) + jblk*8 + (cI & 7);
  const int n1 = n0 + 1024;

  f32x4 acc0 = {0,0,0,0}, acc1 = {0,0,0,0};
  {
    const u16* hH = h0hi + ar*512 + kc;
    const u16* hL = h0lo + ar*512 + kc;
    #pragma unroll 4
    for (int ks = 0; ks < 16; ++ks){
      int k = ks*32;
      short8 ah = *(const short8*)(hH + k);
      short8 al = *(const short8*)(hL + k);
      short8 bh0, bl0, bh1, bl1;
      ldw8s(Wihf + n0*512 + kc + k, bh0, bl0);
      ldw8s(Wihf + n1*512 + kc + k, bh1, bl1);
      SMACC(acc0, ah, al, bh0, bl0);
      SMACC(acc1, ah, al, bh1, bl1);
    }
  }
  {
    const u16* hH = h1phi + ar*512 + kc;
    const u16* hL = h1plo + ar*512 + kc;
    #pragma unroll 4
    for (int ks = 0; ks < 16; ++ks){
      int k = ks*32;
      short8 ah = *(const short8*)(hH + k);
      short8 al = *(const short8*)(hL + k);
      short8 bh0, bl0, bh1, bl1;
      ldw8s(Wihf + n0*512 + kc + k, bh0, bl0);
      ldw8s(Whhf + n1*512 + kc + k, bh1, bl1);
      SMACC(acc0, ah, al, bh0, bl0);
      SMACC(acc1, ah, al, bh1, bl1);
    }
  }
  cell_epilogue_fb(gl, bs, c1, h1nhi, h1nlo, gfout, mrow, jblk, acc0, acc1, wv, lane, tid);
}

__global__ void __launch_bounds__(256) pred_fb(
    const u16* __restrict__ h1hi, const u16* __restrict__ h1lo,
    const float* __restrict__ Wout, const float* __restrict__ bout,
    u16* __restrict__ predhi, u16* __restrict__ predlo,
    float* __restrict__ out, int l)
{
  const int wg = blockIdx.x, tid = threadIdx.x;
  const int bsub = tid >> 6, d = tid & 63;
  const int b = wg*4 + bsub;
  float acc = bout[d];
  const u16* hH = h1hi + b*512;
  const u16* hL = h1lo + b*512;
  const float* wr = Wout + d*512;
  #pragma unroll 8
  for (int k = 0; k < 512; k += 8){
    short8 hv = *(const short8*)(hH + k);
    short8 lv = *(const short8*)(hL + k);
    #pragma unroll
    for (int j = 0; j < 8; ++j)
      acc += (bf2f((u16)hv[j]) + bf2f((u16)lv[j])) * wr[k + j];
  }
  HiLo s = split1(acc);
  predhi[b*64 + d] = (u16)s.hi;
  predlo[b*64 + d] = (u16)s.lo;
  out[131072 + (b*64 + d)*96 + l] = acc;
}

extern "C" void kernel_launch(void* const* d_in, const int* in_sizes, int n_in,
                              void* d_out, int out_size, void* d_ws, size_t ws_size,
                              hipStream_t stream)
{
  const float* x    = (const float*)d_in[0];
  const float* Wih0 = (const float*)d_in[1];
  const float* Whh0 = (const float*)d_in[2];
  const float* bih0 = (const float*)d_in[3];
  const float* bhh0 = (const float*)d_in[4];
  const float* Wih1 = (const float*)d_in[5];
  const float* Whh1 = (const float*)d_in[6];
  const float* bih1 = (const float*)d_in[7];
  const float* bhh1 = (const float*)d_in[8];
  const float* Wout = (const float*)d_in[9];
  const float* bout = (const float*)d_in[10];
  float* out = (float*)d_out;

  // ---- ws layout (main): h 2MB | cnt 64KB | split weights 12MB | bb 8KB
  char* ws = (char*)d_ws;
  u16* h0h[2] = { (u16*)(ws + 0),       (u16*)(ws + 262144) };
  u16* h0l[2] = { (u16*)(ws + 524288),  (u16*)(ws + 786432) };
  u16* h1h[2] = { (u16*)(ws + 1048576), (u16*)(ws + 1310720) };
  u16* h1l[2] = { (u16*)(ws + 1572864), (u16*)(ws + 1835008) };
  unsigned* cnt = (unsigned*)(ws + 2097152);
  u16* Wcmb_h = (u16*)(ws + 2162688);
  u16* Wcmb_l = Wcmb_h + 1048576;
  u16* W1ih_h = Wcmb_l + 1048576;
  u16* W1ih_l = W1ih_h + 1048576;
  u16* W1hh_h = W1ih_l + 1048576;
  u16* W1hh_l = W1hh_h + 1048576;
  float* bb   = (float*)(W1hh_l + 1048576);
  const size_t NEED = 2162688u + 6u*2097152u + 8192u;   // ~14.8 MB
  // fallback layout (only used when ws too small)
  float* fb_c0 = (float*)(ws + 2162688);
  float* fb_c1 = (float*)(ws + 2686976);
  u16* predh   = (u16*)(ws + 3211264);
  u16* predl   = (u16*)(ws + 3244032);
  const bool ps = (ws_size >= NEED);

  (void)hipMemsetAsync(d_ws, 0, 3276800, stream);   // h + cnt (+ fb c/pred)

  if (ps){
    wcomb_k<<<dim3(256), dim3(256), 0, stream>>>(Wih0, Wout, bout, bih0, bhh0,
                                                 Wcmb_h, Wcmb_l, bb);
    wsplit<<<dim3(4096), dim3(256), 0, stream>>>(Wih1, W1ih_h, W1ih_l, 1048576);
    wsplit<<<dim3(4096), dim3(256), 0, stream>>>(Whh1, W1hh_h, W1hh_l, 1048576);
    lstm_persist<<<dim3(256), dim3(256), 0, stream>>>(
        x, Whh0, Wih0, W1ih_h, W1ih_l, W1hh_h, W1hh_l, Wcmb_h, Wcmb_l, bb,
        bih0, bhh0, bih1, bhh1, Wout, bout, out, cnt,
        h0h[0], h0h[1], h0l[0], h0l[1], h1h[0], h1h[1], h1l[0], h1l[1]);
    pred_last<<<dim3(64), dim3(256), 0, stream>>>(h1h[1], h1l[1], Wout, bout, out);
  } else {
    for (int t = 0; t < 432; ++t){
      const int p = t & 1;
      float* gf = (t == 335) ? out : (float*)nullptr;
      if (t < 336)
        l0_fb<true><<<dim3(256), dim3(256), 0, stream>>>(
            x, predh, predl, Wih0, Whh0, bih0, bhh0,
            h0h[p^1], h0l[p^1], h0h[p], h0l[p], fb_c0, t);
      else
        l0_fb<false><<<dim3(256), dim3(256), 0, stream>>>(
            x, predh, predl, Wih0, Whh0, bih0, bhh0,
            h0h[p^1], h0l[p^1], h0h[p], h0l[p], fb_c0, t);
      l1_fb<<<dim3(256), dim3(256), 0, stream>>>(
          Wih1, Whh1, bih1, bhh1, h0h[p], h0l[p],
          h1h[p^1], h1l[p^1], h1h[p], h1l[p], fb_c1, gf);
      if (t >= 336)
        pred_fb<<<dim3(64), dim3(256), 0, stream>>>(
            h1h[p], h1l[p], Wout, bout, predh, predl, out, t - 336);
    }
  }
}